// Round 6
// baseline (645.214 us; speedup 1.0000x reference)
//
#include <hip/hip_runtime.h>
#include <stdint.h>

// DCN-V2 MoE low-rank cross network, fused both layers, bf16 MFMA.
// B=16384 D=1024 R=64 E=4 L=2.
//
// R5 -> R6: raise per-wave intensity instead of occupancy. MTILE=64, grid 256
// (1 block/CU), 4 waves (wave = expert, owns ALL 64 rows = 4 m-frags).
// Every B-frag now feeds 4 MFMAs (B-traffic per row halves; per-CU L1 stream
// ~2.9MB ~= 19us floor), 20 indep MFMAs per kt hide latency, depth-2 B
// prefetch (triple buffer, constant-indexed arrays, no lambdas) covers ~2x
// iteration time ~= L2 latency. 1 wave/SIMD by design (R5 showed we end up
// there anyway); arch VGPR kept <= 256. LDS = 160KB exactly:
//   xl [64][1024] bf16 swizzled (128KB) | sh 32KB: v [E][64][64] -> gc [64][256]

typedef __attribute__((ext_vector_type(8))) short bf16x8;
typedef __attribute__((ext_vector_type(4))) float f32x4;

#define MFMA_BF16(a, b, c) __builtin_amdgcn_mfma_f32_16x16x32_bf16((a), (b), (c), 0, 0, 0)

static constexpr int kB = 16384, kD = 1024;
static constexpr int MTILE = 64;

// workspace layout in ushort elems
static constexpr size_t W1F_OFF = 0;                         // [L][32 kt][17 nt][64][8]
static constexpr size_t W1F_SZ  = 2ull * 32 * 17 * 64 * 8;   // 557056
static constexpr size_t W2F_OFF = W1F_OFF + W1F_SZ;          // [L][8 kt][64 nt][64][8]
static constexpr size_t W2F_SZ  = 2ull * 8 * 64 * 64 * 8;    // 524288
static constexpr size_t CF_OFF  = W2F_OFF + W2F_SZ;          // [L][E][2 kt][4 nt][64][8]

__device__ __forceinline__ unsigned short f2bf(float f) {
    uint32_t u = __builtin_bit_cast(uint32_t, f);
    u = (u + 0x7FFFu + ((u >> 16) & 1u)) >> 16;   // RNE
    return (unsigned short)u;
}
__device__ __forceinline__ float bf2f(unsigned short h) {
    uint32_t u = ((uint32_t)h) << 16;
    return __builtin_bit_cast(float, u);
}
__device__ __forceinline__ float fast_tanh(float x) {
    float e = __builtin_amdgcn_exp2f(x * 2.8853900817779268f);
    return 1.0f - 2.0f * __builtin_amdgcn_rcpf(e + 1.0f);
}
__device__ __forceinline__ float fast_exp(float x) {
    return __builtin_amdgcn_exp2f(x * 1.4426950408889634f);
}

// ---------------- weight prep: fp32 -> bf16 MFMA B-fragments ----------------
__global__ __launch_bounds__(256) void prep_weights(
    const float* __restrict__ U, const float* __restrict__ V,
    const float* __restrict__ C, const float* __restrict__ gateW,
    unsigned short* __restrict__ ws)
{
    const int id = blockIdx.x * 256 + threadIdx.x;
    const int lane = id & 63;
    const int kg = lane >> 4, c = lane & 15;
    if (id < 2 * 32 * 17 * 64) {                       // W1 fragments (V transpose: scalar)
        int t = id >> 6;
        int nt = t % 17; t /= 17;
        int kt = t & 31; int i = t >> 5;
        int col = nt * 16 + c;
        bf16x8 o;
#pragma unroll
        for (int j = 0; j < 8; ++j) {
            int k = kt * 32 + kg * 8 + j;              // k = d
            float v = 0.0f;
            if (col < 256) {
                int e = col >> 6, r = col & 63;
                v = V[((size_t)(i * 4 + e) * 1024 + k) * 64 + r];
            } else if (col < 260) {
                v = gateW[(size_t)(col - 256) * 1024 + k];
            }
            o[j] = (short)f2bf(v);
        }
        *(bf16x8*)(ws + W1F_OFF + (size_t)id * 8) = o;
    } else if (id < 2 * 32 * 17 * 64 + 2 * 8 * 64 * 64) {  // W2 fragments (r consecutive: f32x4)
        int id2 = id - 2 * 32 * 17 * 64;
        int t = id2 >> 6;
        int nt = t & 63; t >>= 6;
        int kt = t & 7;  int i = t >> 3;
        int d = nt * 16 + c;
        int k0 = kt * 32 + kg * 8;
        int e = k0 >> 6, r0 = k0 & 63;
        const float* src = U + ((size_t)(i * 4 + e) * 1024 + d) * 64 + r0;
        f32x4 u0 = *(const f32x4*)src;
        f32x4 u1 = *(const f32x4*)(src + 4);
        bf16x8 o;
        o[0] = (short)f2bf(u0[0]); o[1] = (short)f2bf(u0[1]);
        o[2] = (short)f2bf(u0[2]); o[3] = (short)f2bf(u0[3]);
        o[4] = (short)f2bf(u1[0]); o[5] = (short)f2bf(u1[1]);
        o[6] = (short)f2bf(u1[2]); o[7] = (short)f2bf(u1[3]);
        *(bf16x8*)(ws + W2F_OFF + (size_t)id2 * 8) = o;
    } else if (id < 2 * 32 * 17 * 64 + 2 * 8 * 64 * 64 + 2 * 4 * 2 * 4 * 64) {  // C frags (q consecutive)
        int id3 = id - (2 * 32 * 17 * 64 + 2 * 8 * 64 * 64);
        int t = id3 >> 6;
        int nt = t & 3; t >>= 2;
        int kt = t & 1; t >>= 1;
        int e = t & 3;  int i = t >> 2;
        int r = nt * 16 + c;
        int q0 = kt * 32 + kg * 8;
        const float* src = C + ((size_t)(i * 4 + e) * 64 + r) * 64 + q0;
        f32x4 c0 = *(const f32x4*)src;
        f32x4 c1 = *(const f32x4*)(src + 4);
        bf16x8 o;
        o[0] = (short)f2bf(c0[0]); o[1] = (short)f2bf(c0[1]);
        o[2] = (short)f2bf(c0[2]); o[3] = (short)f2bf(c0[3]);
        o[4] = (short)f2bf(c1[0]); o[5] = (short)f2bf(c1[1]);
        o[6] = (short)f2bf(c1[2]); o[7] = (short)f2bf(c1[3]);
        *(bf16x8*)(ws + CF_OFF + (size_t)id3 * 8) = o;
    }
}

// ---------------- fused main kernel (256 threads, 4 waves, M=64) ----------------
__global__ __launch_bounds__(256) void dcn_main(
    const float* __restrict__ x, const float* __restrict__ bias,
    const unsigned short* __restrict__ ws, float* __restrict__ out)
{
    __shared__ char smem[160 * 1024];   // 128K xl + 32K sh -> 1 block/CU
    char* xl = smem;                    // x_l tile [64][1024] bf16, XOR-swizzled
    char* sh = smem + 128 * 1024;       // v slices [E][64][64] bf16, then gc [64][256]

    const unsigned short* w1f = ws + W1F_OFF;
    const unsigned short* w2f = ws + W2F_OFF;
    const unsigned short* cf  = ws + CF_OFF;

    const int tid = threadIdx.x;
    const int lane = tid & 63, wid = tid >> 6;      // wid 0..3 = expert
    const int kg = lane >> 4, lc = lane & 15;
    const int mbase = blockIdx.x * MTILE;

    // ---- stage x -> xl (bf16, swizzled): 64 rows x 1024 cols ----
#pragma unroll
    for (int it = 0; it < 32; ++it) {
        int chunk = it * 256 + tid;                 // 8-float chunks, 64*128 total
        int row = chunk >> 7, col = (chunk & 127) * 8;
        const float* src = x + (size_t)(mbase + row) * 1024 + col;
        f32x4 v0 = *(const f32x4*)src;
        f32x4 v1 = *(const f32x4*)(src + 4);
        bf16x8 hv;
        hv[0] = (short)f2bf(v0[0]); hv[1] = (short)f2bf(v0[1]);
        hv[2] = (short)f2bf(v0[2]); hv[3] = (short)f2bf(v0[3]);
        hv[4] = (short)f2bf(v1[0]); hv[5] = (short)f2bf(v1[1]);
        hv[6] = (short)f2bf(v1[2]); hv[7] = (short)f2bf(v1[3]);
        int off = (row * 2048 + col * 2) ^ ((row & 7) << 4);
        *(bf16x8*)(xl + off) = hv;
    }
    __syncthreads();

    const f32x4 zf = {0.f, 0.f, 0.f, 0.f};

    for (int i = 0; i < 2; ++i) {
        // ---------- Phase A: GEMM1 Y[64,80] per wave (4 expert nt + gate) ----------
        // depth-2 B prefetch (triple buffer), depth-1 A prefetch; all indices
        // compile-time constants after full unroll (rule #20).
        f32x4 acc1[4][4];
        f32x4 accg[4];
#pragma unroll
        for (int mt = 0; mt < 4; ++mt) {
            accg[mt] = zf;
#pragma unroll
            for (int nt = 0; nt < 4; ++nt) acc1[mt][nt] = zf;
        }
        bf16x8 bb[3][5];
        bf16x8 ab[2][4];
        {
            const unsigned short* wb0 = w1f + (size_t)(i * 32 + 0) * 17 * 512;
            const unsigned short* wb1 = w1f + (size_t)(i * 32 + 1) * 17 * 512;
#pragma unroll
            for (int nt = 0; nt < 4; ++nt) {
                bb[0][nt] = *(const bf16x8*)(wb0 + (4 * wid + nt) * 512 + lane * 8);
                bb[1][nt] = *(const bf16x8*)(wb1 + (4 * wid + nt) * 512 + lane * 8);
            }
            bb[0][4] = *(const bf16x8*)(wb0 + 16 * 512 + lane * 8);
            bb[1][4] = *(const bf16x8*)(wb1 + 16 * 512 + lane * 8);
#pragma unroll
            for (int mt = 0; mt < 4; ++mt) {
                int row = mt * 16 + lc;
                int off = (row * 2048 + (kg * 8) * 2) ^ ((row & 7) << 4);
                ab[0][mt] = *(const bf16x8*)(xl + off);
            }
        }
#pragma unroll
        for (int kt = 0; kt < 32; ++kt) {
            const int cur3 = kt % 3, nx3 = (kt + 2) % 3;
            const int cur2 = kt & 1, nx2 = (kt + 1) & 1;
            if (kt < 30) {                           // issue B loads 2 iters ahead
                const unsigned short* wb = w1f + (size_t)(i * 32 + kt + 2) * 17 * 512;
#pragma unroll
                for (int nt = 0; nt < 4; ++nt)
                    bb[nx3][nt] = *(const bf16x8*)(wb + (4 * wid + nt) * 512 + lane * 8);
                bb[nx3][4] = *(const bf16x8*)(wb + 16 * 512 + lane * 8);
            }
            if (kt < 31) {                           // A frags 1 iter ahead
#pragma unroll
                for (int mt = 0; mt < 4; ++mt) {
                    int row = mt * 16 + lc;
                    int off = (row * 2048 + ((kt + 1) * 32 + kg * 8) * 2) ^ ((row & 7) << 4);
                    ab[nx2][mt] = *(const bf16x8*)(xl + off);
                }
            }
#pragma unroll
            for (int mt = 0; mt < 4; ++mt) {
#pragma unroll
                for (int nt = 0; nt < 4; ++nt)
                    acc1[mt][nt] = MFMA_BF16(ab[cur2][mt], bb[cur3][nt], acc1[mt][nt]);
                accg[mt] = MFMA_BF16(ab[cur2][mt], bb[cur3][4], accg[mt]);
            }
        }

        // ---------- early-issue Phase B C-fragments (hide under gate + v) ----------
        bf16x8 cb[8];
        {
            const unsigned short* cbase = cf + (size_t)((i * 4 + wid) * 2) * 4 * 512;
#pragma unroll
            for (int q = 0; q < 8; ++q)
                cb[q] = *(const bf16x8*)(cbase + q * 512 + lane * 8);
        }

        // ---------- gate softmax (keep expert wid) ----------
        float gate_val[4][4];
#pragma unroll
        for (int mt = 0; mt < 4; ++mt)
#pragma unroll
        for (int j = 0; j < 4; ++j) {
            int base = lane & 48;
            float l0 = __shfl(accg[mt][j], base + 0);
            float l1 = __shfl(accg[mt][j], base + 1);
            float l2 = __shfl(accg[mt][j], base + 2);
            float l3 = __shfl(accg[mt][j], base + 3);
            float m = fmaxf(fmaxf(l0, l1), fmaxf(l2, l3));
            float e0 = fast_exp(l0 - m), e1 = fast_exp(l1 - m);
            float e2 = fast_exp(l2 - m), e3 = fast_exp(l3 - m);
            float ge = wid == 0 ? e0 : wid == 1 ? e1 : wid == 2 ? e2 : e3;
            gate_val[mt][j] = ge * __builtin_amdgcn_rcpf(e0 + e1 + e2 + e3);
        }

        // ---------- v = tanh(Y) -> own expert slice [64][64] (wave-private) ----------
        char* vsl = sh + wid * 8192;
#pragma unroll
        for (int mt = 0; mt < 4; ++mt)
#pragma unroll
        for (int nt = 0; nt < 4; ++nt)
#pragma unroll
        for (int j = 0; j < 4; ++j) {
            int row = mt * 16 + kg * 4 + j;
            int q = nt * 16 + lc;
            int off = (row * 128 + q * 2) ^ ((row & 7) << 4);
            *(unsigned short*)(vsl + off) = f2bf(fast_tanh(acc1[mt][nt][j]));
        }
        // no barrier: Phase B reads only this wave's own slice

        // ---------- Phase B: c = v @ C[e]^T (32 MFMA) ----------
        f32x4 accc[4][4];
#pragma unroll
        for (int mt = 0; mt < 4; ++mt)
#pragma unroll
        for (int nt = 0; nt < 4; ++nt) accc[mt][nt] = zf;
        {
            bf16x8 va[2][4];
#pragma unroll
            for (int kt = 0; kt < 2; ++kt)
#pragma unroll
            for (int mt = 0; mt < 4; ++mt) {
                int row = mt * 16 + lc;
                int off = (row * 128 + (kt * 32 + kg * 8) * 2) ^ ((row & 7) << 4);
                va[kt][mt] = *(const bf16x8*)(vsl + off);
            }
#pragma unroll
            for (int kt = 0; kt < 2; ++kt)
#pragma unroll
            for (int nt = 0; nt < 4; ++nt)
#pragma unroll
            for (int mt = 0; mt < 4; ++mt)
                accc[mt][nt] = MFMA_BF16(va[kt][mt], cb[kt * 4 + nt], accc[mt][nt]);
        }
        __syncthreads();   // all v reads done; re-purpose sh as gc

        // ---------- gc = gate_e * tanh(c) -> sh as [64][256] bf16 swizzled ----------
#pragma unroll
        for (int mt = 0; mt < 4; ++mt)
#pragma unroll
        for (int nt = 0; nt < 4; ++nt)
#pragma unroll
        for (int j = 0; j < 4; ++j) {
            int row = mt * 16 + kg * 4 + j;
            int colg = wid * 64 + nt * 16 + lc;
            float t = fast_tanh(accc[mt][nt][j]) * gate_val[mt][j];
            int off = (row * 512 + colg * 2) ^ ((row & 7) << 4);
            *(unsigned short*)(sh + off) = f2bf(t);
        }
        __syncthreads();

        // ---------- Phase C: Z = gc @ W2 (wave owns 256 d-cols, 4 passes x 4 nt) ----------
#pragma unroll
        for (int pass = 0; pass < 4; ++pass) {
            f32x4 acc2[4][4];
#pragma unroll
            for (int mt = 0; mt < 4; ++mt)
#pragma unroll
            for (int nt = 0; nt < 4; ++nt) acc2[mt][nt] = zf;

            bf16x8 cb3[3][4];
            bf16x8 a2[2][4];
            {
                const unsigned short* w0 = w2f + (size_t)(i * 8 + 0) * 64 * 512;
                const unsigned short* w1 = w2f + (size_t)(i * 8 + 1) * 64 * 512;
#pragma unroll
                for (int nt = 0; nt < 4; ++nt) {
                    cb3[0][nt] = *(const bf16x8*)(w0 + (wid * 16 + pass * 4 + nt) * 512 + lane * 8);
                    cb3[1][nt] = *(const bf16x8*)(w1 + (wid * 16 + pass * 4 + nt) * 512 + lane * 8);
                }
#pragma unroll
                for (int mt = 0; mt < 4; ++mt) {
                    int row = mt * 16 + lc;
                    int off = (row * 512 + (kg * 8) * 2) ^ ((row & 7) << 4);
                    a2[0][mt] = *(const bf16x8*)(sh + off);
                }
            }
#pragma unroll
            for (int kt = 0; kt < 8; ++kt) {
                const int cur3 = kt % 3, nx3 = (kt + 2) % 3;
                const int cur2 = kt & 1, nx2 = (kt + 1) & 1;
                if (kt < 6) {
                    const unsigned short* w2b = w2f + (size_t)(i * 8 + kt + 2) * 64 * 512;
#pragma unroll
                    for (int nt = 0; nt < 4; ++nt)
                        cb3[nx3][nt] = *(const bf16x8*)(w2b + (wid * 16 + pass * 4 + nt) * 512 + lane * 8);
                }
                if (kt < 7) {
#pragma unroll
                    for (int mt = 0; mt < 4; ++mt) {
                        int row = mt * 16 + lc;
                        int off = (row * 512 + ((kt + 1) * 32 + kg * 8) * 2) ^ ((row & 7) << 4);
                        a2[nx2][mt] = *(const bf16x8*)(sh + off);
                    }
                }
#pragma unroll
                for (int mt = 0; mt < 4; ++mt)
#pragma unroll
                for (int nt = 0; nt < 4; ++nt)
                    acc2[mt][nt] = MFMA_BF16(a2[cur2][mt], cb3[cur3][nt], acc2[mt][nt]);
            }

            // ---------- fused epilogue: out = x0 .* (Z + bias) + x_l ----------
#pragma unroll
            for (int nt = 0; nt < 4; ++nt) {
                int d = wid * 256 + pass * 64 + nt * 16 + lc;
                float bv = bias[(size_t)i * 1024 + d];
#pragma unroll
                for (int mt = 0; mt < 4; ++mt)
#pragma unroll
                for (int j = 0; j < 4; ++j) {
                    int row = mt * 16 + kg * 4 + j;
                    float z = acc2[mt][nt][j] + bv;
                    float x0v = x[(size_t)(mbase + row) * 1024 + d];
                    int xoff = (row * 2048 + d * 2) ^ ((row & 7) << 4);
                    float xlv = bf2f(*(const unsigned short*)(xl + xoff));
                    float o = x0v * z + xlv;                // x0*(Z+bias) + x_l
                    if (i == 0) {
                        *(unsigned short*)(xl + xoff) = f2bf(o);   // next layer's x_l
                    } else {
                        out[(size_t)(mbase + row) * 1024 + d] = o;
                    }
                }
            }
        }
        __syncthreads();   // xl rewritten / sh reused next layer
    }
}

extern "C" void kernel_launch(void* const* d_in, const int* in_sizes, int n_in,
                              void* d_out, int out_size, void* d_ws, size_t ws_size,
                              hipStream_t stream) {
    const float* x     = (const float*)d_in[0];
    const float* U     = (const float*)d_in[1];
    const float* V     = (const float*)d_in[2];
    const float* C     = (const float*)d_in[3];
    const float* bias  = (const float*)d_in[4];
    const float* gateW = (const float*)d_in[5];
    unsigned short* ws = (unsigned short*)d_ws;
    float* out = (float*)d_out;

    const int prep_threads = 2 * 32 * 17 * 64 + 2 * 8 * 64 * 64 + 2 * 4 * 2 * 4 * 64; // 139264
    prep_weights<<<(prep_threads + 255) / 256, 256, 0, stream>>>(U, V, C, gateW, ws);
    dcn_main<<<kB / MTILE, 256, 0, stream>>>(x, bias, ws, out);
}

// Round 7
// 410.629 us; speedup vs baseline: 1.5713x; 1.5713x over previous
//
#include <hip/hip_runtime.h>
#include <stdint.h>

// DCN-V2 MoE low-rank cross network, fused both layers, bf16 MFMA.
// B=16384 D=1024 R=64 E=4 L=2.
//
// R6 -> R7: combine the two measured laws from R1-R6:
//   (a) VGPR_Count <= 128 -> 2 blocks/CU (22% occ); > 128 -> 1 block/CU (11%).
//       R2 (cap 128, even WITH 50MB spills) = 171us beat everything.
//   (b) lambda-pointer staging buffers = local-memory arrays = scratch
//       (R3/R4/R6 disasters); plain arrays + constant indices = clean (R1/R5).
// R7 = R5's plain-array no-lambda body + R2's __launch_bounds__(256,2) cap,
// with cb C-frag loads moved late (live-range slim). One controlled change.
//
// Wave roles (wid 0..3 = expert e), per layer, per 32-row block:
//   Phase A: GEMM1 Y[32,272] = x_l @ W1; wave owns nt {4w..4w+3} + gate frag.
//   v = tanh(Y) -> own LDS slice [32][64] (wave-private, no barrier).
//   Phase B: c = v @ C[e]^T (16 MFMA).
//   barrier. gc = gate_e * tanh(c) -> LDS [32][256]. barrier.
//   Phase C: Z = gc @ W2; wave owns 16 d-tiles, 4 passes x 4, depth-1 B dbuf.
//   epilogue: out = x0 .* (Z + bias) + x_l; layer0 re-stages xl.

typedef __attribute__((ext_vector_type(8))) short bf16x8;
typedef __attribute__((ext_vector_type(4))) float f32x4;

#define MFMA_BF16(a, b, c) __builtin_amdgcn_mfma_f32_16x16x32_bf16((a), (b), (c), 0, 0, 0)

static constexpr int kB = 16384, kD = 1024;
static constexpr int MTILE = 32;

// workspace layout in ushort elems
static constexpr size_t W1F_OFF = 0;                         // [L][32 kt][17 nt][64][8]
static constexpr size_t W1F_SZ  = 2ull * 32 * 17 * 64 * 8;   // 557056
static constexpr size_t W2F_OFF = W1F_OFF + W1F_SZ;          // [L][8 kt][64 nt][64][8]
static constexpr size_t W2F_SZ  = 2ull * 8 * 64 * 64 * 8;    // 524288
static constexpr size_t CF_OFF  = W2F_OFF + W2F_SZ;          // [L][E][2 kt][4 nt][64][8]

__device__ __forceinline__ unsigned short f2bf(float f) {
    uint32_t u = __builtin_bit_cast(uint32_t, f);
    u = (u + 0x7FFFu + ((u >> 16) & 1u)) >> 16;   // RNE
    return (unsigned short)u;
}
__device__ __forceinline__ float bf2f(unsigned short h) {
    uint32_t u = ((uint32_t)h) << 16;
    return __builtin_bit_cast(float, u);
}
__device__ __forceinline__ float fast_tanh(float x) {
    float e = __builtin_amdgcn_exp2f(x * 2.8853900817779268f);
    return 1.0f - 2.0f * __builtin_amdgcn_rcpf(e + 1.0f);
}
__device__ __forceinline__ float fast_exp(float x) {
    return __builtin_amdgcn_exp2f(x * 1.4426950408889634f);
}

// ---------------- weight prep: fp32 -> bf16 MFMA B-fragments ----------------
__global__ __launch_bounds__(256) void prep_weights(
    const float* __restrict__ U, const float* __restrict__ V,
    const float* __restrict__ C, const float* __restrict__ gateW,
    unsigned short* __restrict__ ws)
{
    const int id = blockIdx.x * 256 + threadIdx.x;
    const int lane = id & 63;
    const int kg = lane >> 4, c = lane & 15;
    if (id < 2 * 32 * 17 * 64) {                       // W1 fragments (V transpose: scalar)
        int t = id >> 6;
        int nt = t % 17; t /= 17;
        int kt = t & 31; int i = t >> 5;
        int col = nt * 16 + c;
        bf16x8 o;
#pragma unroll
        for (int j = 0; j < 8; ++j) {
            int k = kt * 32 + kg * 8 + j;              // k = d
            float v = 0.0f;
            if (col < 256) {
                int e = col >> 6, r = col & 63;
                v = V[((size_t)(i * 4 + e) * 1024 + k) * 64 + r];
            } else if (col < 260) {
                v = gateW[(size_t)(col - 256) * 1024 + k];
            }
            o[j] = (short)f2bf(v);
        }
        *(bf16x8*)(ws + W1F_OFF + (size_t)id * 8) = o;
    } else if (id < 2 * 32 * 17 * 64 + 2 * 8 * 64 * 64) {  // W2 fragments (r consecutive: f32x4)
        int id2 = id - 2 * 32 * 17 * 64;
        int t = id2 >> 6;
        int nt = t & 63; t >>= 6;
        int kt = t & 7;  int i = t >> 3;
        int d = nt * 16 + c;
        int k0 = kt * 32 + kg * 8;
        int e = k0 >> 6, r0 = k0 & 63;
        const float* src = U + ((size_t)(i * 4 + e) * 1024 + d) * 64 + r0;
        f32x4 u0 = *(const f32x4*)src;
        f32x4 u1 = *(const f32x4*)(src + 4);
        bf16x8 o;
        o[0] = (short)f2bf(u0[0]); o[1] = (short)f2bf(u0[1]);
        o[2] = (short)f2bf(u0[2]); o[3] = (short)f2bf(u0[3]);
        o[4] = (short)f2bf(u1[0]); o[5] = (short)f2bf(u1[1]);
        o[6] = (short)f2bf(u1[2]); o[7] = (short)f2bf(u1[3]);
        *(bf16x8*)(ws + W2F_OFF + (size_t)id2 * 8) = o;
    } else if (id < 2 * 32 * 17 * 64 + 2 * 8 * 64 * 64 + 2 * 4 * 2 * 4 * 64) {  // C frags (q consecutive)
        int id3 = id - (2 * 32 * 17 * 64 + 2 * 8 * 64 * 64);
        int t = id3 >> 6;
        int nt = t & 3; t >>= 2;
        int kt = t & 1; t >>= 1;
        int e = t & 3;  int i = t >> 2;
        int r = nt * 16 + c;
        int q0 = kt * 32 + kg * 8;
        const float* src = C + ((size_t)(i * 4 + e) * 64 + r) * 64 + q0;
        f32x4 c0 = *(const f32x4*)src;
        f32x4 c1 = *(const f32x4*)(src + 4);
        bf16x8 o;
        o[0] = (short)f2bf(c0[0]); o[1] = (short)f2bf(c0[1]);
        o[2] = (short)f2bf(c0[2]); o[3] = (short)f2bf(c0[3]);
        o[4] = (short)f2bf(c1[0]); o[5] = (short)f2bf(c1[1]);
        o[6] = (short)f2bf(c1[2]); o[7] = (short)f2bf(c1[3]);
        *(bf16x8*)(ws + CF_OFF + (size_t)id3 * 8) = o;
    }
}

// ---------------- fused main kernel (256 threads, 4 waves, cap 128) ----------------
__global__ __launch_bounds__(256, 2) void dcn_main(
    const float* __restrict__ x, const float* __restrict__ bias,
    const unsigned short* __restrict__ ws, float* __restrict__ out)
{
    __shared__ char smem[80 * 1024];    // 64K xl + 16K sh -> 2 blocks/CU
    char* xl = smem;                    // x_l tile [32][1024] bf16, XOR-swizzled
    char* sh = smem + 64 * 1024;        // v slices [E][32][64] bf16, then gc [32][256]

    const unsigned short* w1f = ws + W1F_OFF;
    const unsigned short* w2f = ws + W2F_OFF;
    const unsigned short* cf  = ws + CF_OFF;

    const int tid = threadIdx.x;
    const int lane = tid & 63, wid = tid >> 6;      // wid 0..3 = expert
    const int kg = lane >> 4, lc = lane & 15;
    const int mbase = blockIdx.x * MTILE;

    // ---- stage x -> xl (bf16, swizzled) ----
#pragma unroll
    for (int it = 0; it < 16; ++it) {
        int chunk = it * 256 + tid;                 // 8-float chunks, 32*128 total
        int row = chunk >> 7, col = (chunk & 127) * 8;
        const float* src = x + (size_t)(mbase + row) * 1024 + col;
        f32x4 v0 = *(const f32x4*)src;
        f32x4 v1 = *(const f32x4*)(src + 4);
        bf16x8 hv;
        hv[0] = (short)f2bf(v0[0]); hv[1] = (short)f2bf(v0[1]);
        hv[2] = (short)f2bf(v0[2]); hv[3] = (short)f2bf(v0[3]);
        hv[4] = (short)f2bf(v1[0]); hv[5] = (short)f2bf(v1[1]);
        hv[6] = (short)f2bf(v1[2]); hv[7] = (short)f2bf(v1[3]);
        int off = (row * 2048 + col * 2) ^ ((row & 7) << 4);
        *(bf16x8*)(xl + off) = hv;
    }
    __syncthreads();

    const f32x4 zf = {0.f, 0.f, 0.f, 0.f};

    for (int i = 0; i < 2; ++i) {
        // ---------- Phase A: GEMM1, wave owns nt {4w..4w+3} + gate ----------
        // depth-1 B dbuf, plain arrays + constant indices (no lambdas/pointers)
        f32x4 acc1[2][4] = {{zf, zf, zf, zf}, {zf, zf, zf, zf}};
        f32x4 accg[2] = {zf, zf};
        bf16x8 bcur[5], bnxt[5];
        {
            const unsigned short* wb = w1f + (size_t)(i * 32) * 17 * 512;
#pragma unroll
            for (int nt = 0; nt < 4; ++nt)
                bcur[nt] = *(const bf16x8*)(wb + (4 * wid + nt) * 512 + lane * 8);
            bcur[4] = *(const bf16x8*)(wb + 16 * 512 + lane * 8);
        }
#pragma unroll
        for (int kt = 0; kt < 32; ++kt) {
            if (kt < 31) {                           // issue next-kt B loads first
                const unsigned short* wb = w1f + (size_t)(i * 32 + kt + 1) * 17 * 512;
#pragma unroll
                for (int nt = 0; nt < 4; ++nt)
                    bnxt[nt] = *(const bf16x8*)(wb + (4 * wid + nt) * 512 + lane * 8);
                bnxt[4] = *(const bf16x8*)(wb + 16 * 512 + lane * 8);
            }
            int koff = (kt * 32 + kg * 8) * 2;
            int r0 = lc, r1 = 16 + lc;
            bf16x8 a0 = *(const bf16x8*)(xl + ((r0 * 2048 + koff) ^ ((r0 & 7) << 4)));
            bf16x8 a1 = *(const bf16x8*)(xl + ((r1 * 2048 + koff) ^ ((r1 & 7) << 4)));
#pragma unroll
            for (int nt = 0; nt < 4; ++nt) {
                acc1[0][nt] = MFMA_BF16(a0, bcur[nt], acc1[0][nt]);
                acc1[1][nt] = MFMA_BF16(a1, bcur[nt], acc1[1][nt]);
            }
            accg[0] = MFMA_BF16(a0, bcur[4], accg[0]);
            accg[1] = MFMA_BF16(a1, bcur[4], accg[1]);
            if (kt < 31) {
#pragma unroll
                for (int q = 0; q < 5; ++q) bcur[q] = bnxt[q];
            }
        }

        // ---------- gate softmax (keep expert wid) ----------
        float gate_val[2][4];
#pragma unroll
        for (int mt = 0; mt < 2; ++mt)
#pragma unroll
        for (int j = 0; j < 4; ++j) {
            int base = lane & 48;
            float l0 = __shfl(accg[mt][j], base + 0);
            float l1 = __shfl(accg[mt][j], base + 1);
            float l2 = __shfl(accg[mt][j], base + 2);
            float l3 = __shfl(accg[mt][j], base + 3);
            float m = fmaxf(fmaxf(l0, l1), fmaxf(l2, l3));
            float e0 = fast_exp(l0 - m), e1 = fast_exp(l1 - m);
            float e2 = fast_exp(l2 - m), e3 = fast_exp(l3 - m);
            float ge = wid == 0 ? e0 : wid == 1 ? e1 : wid == 2 ? e2 : e3;
            gate_val[mt][j] = ge * __builtin_amdgcn_rcpf(e0 + e1 + e2 + e3);
        }

        // ---------- v = tanh(Y) -> own expert slice [32][64] ----------
        char* vsl = sh + wid * 4096;
#pragma unroll
        for (int mt = 0; mt < 2; ++mt)
#pragma unroll
        for (int nt = 0; nt < 4; ++nt)
#pragma unroll
        for (int j = 0; j < 4; ++j) {
            int row = mt * 16 + kg * 4 + j;
            int q = nt * 16 + lc;
            int off = (row * 128 + q * 2) ^ ((row & 7) << 4);
            *(unsigned short*)(vsl + off) = f2bf(fast_tanh(acc1[mt][nt][j]));
        }
        // no barrier: Phase B reads only this wave's own slice (lgkmcnt orders)

        // ---------- Phase B: c = v @ C[e]^T (C-frags loaded here, short live range) ----------
        f32x4 accc[2][4] = {{zf, zf, zf, zf}, {zf, zf, zf, zf}};
        {
            bf16x8 cb[8];
            const unsigned short* cbase = cf + (size_t)((i * 4 + wid) * 2) * 4 * 512;
#pragma unroll
            for (int q = 0; q < 8; ++q)
                cb[q] = *(const bf16x8*)(cbase + q * 512 + lane * 8);
            bf16x8 va[2][2];
#pragma unroll
            for (int kt = 0; kt < 2; ++kt)
#pragma unroll
            for (int mt = 0; mt < 2; ++mt) {
                int row = mt * 16 + lc;
                int off = (row * 128 + (kt * 32 + kg * 8) * 2) ^ ((row & 7) << 4);
                va[kt][mt] = *(const bf16x8*)(vsl + off);
            }
#pragma unroll
            for (int kt = 0; kt < 2; ++kt)
#pragma unroll
            for (int nt = 0; nt < 4; ++nt) {
                accc[0][nt] = MFMA_BF16(va[kt][0], cb[kt * 4 + nt], accc[0][nt]);
                accc[1][nt] = MFMA_BF16(va[kt][1], cb[kt * 4 + nt], accc[1][nt]);
            }
        }
        __syncthreads();   // all v reads done; re-purpose sh as gc

        // ---------- gc = gate_e * tanh(c) -> sh as [32][256] bf16 swizzled ----------
#pragma unroll
        for (int mt = 0; mt < 2; ++mt)
#pragma unroll
        for (int nt = 0; nt < 4; ++nt)
#pragma unroll
        for (int j = 0; j < 4; ++j) {
            int row = mt * 16 + kg * 4 + j;
            int colg = wid * 64 + nt * 16 + lc;
            float t = fast_tanh(accc[mt][nt][j]) * gate_val[mt][j];
            int off = (row * 512 + colg * 2) ^ ((row & 7) << 4);
            *(unsigned short*)(sh + off) = f2bf(t);
        }
        __syncthreads();

        // ---------- Phase C: Z = gc @ W2 (wave owns 16 d-tiles, 4 passes x 4) ----------
#pragma unroll
        for (int pass = 0; pass < 4; ++pass) {
            f32x4 acc2[2][4] = {{zf, zf, zf, zf}, {zf, zf, zf, zf}};
            bf16x8 ccur[4], cnxt[4];
            {
                const unsigned short* w2b = w2f + (size_t)(i * 8) * 64 * 512;
#pragma unroll
                for (int nt = 0; nt < 4; ++nt)
                    ccur[nt] = *(const bf16x8*)(w2b + (wid * 16 + pass * 4 + nt) * 512 + lane * 8);
            }
#pragma unroll
            for (int kt = 0; kt < 8; ++kt) {
                if (kt < 7) {                        // issue next-kt B loads first
                    const unsigned short* w2b = w2f + (size_t)(i * 8 + kt + 1) * 64 * 512;
#pragma unroll
                    for (int nt = 0; nt < 4; ++nt)
                        cnxt[nt] = *(const bf16x8*)(w2b + (wid * 16 + pass * 4 + nt) * 512 + lane * 8);
                }
                int koff = (kt * 32 + kg * 8) * 2;
                int r0 = lc, r1 = 16 + lc;
                bf16x8 a0 = *(const bf16x8*)(sh + ((r0 * 512 + koff) ^ ((r0 & 7) << 4)));
                bf16x8 a1 = *(const bf16x8*)(sh + ((r1 * 512 + koff) ^ ((r1 & 7) << 4)));
#pragma unroll
                for (int nt = 0; nt < 4; ++nt) {
                    acc2[0][nt] = MFMA_BF16(a0, ccur[nt], acc2[0][nt]);
                    acc2[1][nt] = MFMA_BF16(a1, ccur[nt], acc2[1][nt]);
                }
                if (kt < 7) {
#pragma unroll
                    for (int q = 0; q < 4; ++q) ccur[q] = cnxt[q];
                }
            }

            // ---------- fused epilogue: out = x0 .* (Z + bias) + x_l ----------
#pragma unroll
            for (int nt = 0; nt < 4; ++nt) {
                int d = wid * 256 + pass * 64 + nt * 16 + lc;
                float bv = bias[(size_t)i * 1024 + d];
#pragma unroll
                for (int mt = 0; mt < 2; ++mt)
#pragma unroll
                for (int j = 0; j < 4; ++j) {
                    int row = mt * 16 + kg * 4 + j;
                    float z = acc2[mt][nt][j] + bv;
                    float x0v = x[(size_t)(mbase + row) * 1024 + d];
                    int xoff = (row * 2048 + d * 2) ^ ((row & 7) << 4);
                    float xlv = bf2f(*(const unsigned short*)(xl + xoff));
                    float o = x0v * z + xlv;                // x0*(Z+bias) + x_l
                    if (i == 0) {
                        *(unsigned short*)(xl + xoff) = f2bf(o);   // next layer's x_l
                    } else {
                        out[(size_t)(mbase + row) * 1024 + d] = o;
                    }
                }
            }
        }
        __syncthreads();   // xl rewritten / sh reused next layer
    }
}

extern "C" void kernel_launch(void* const* d_in, const int* in_sizes, int n_in,
                              void* d_out, int out_size, void* d_ws, size_t ws_size,
                              hipStream_t stream) {
    const float* x     = (const float*)d_in[0];
    const float* U     = (const float*)d_in[1];
    const float* V     = (const float*)d_in[2];
    const float* C     = (const float*)d_in[3];
    const float* bias  = (const float*)d_in[4];
    const float* gateW = (const float*)d_in[5];
    unsigned short* ws = (unsigned short*)d_ws;
    float* out = (float*)d_out;

    const int prep_threads = 2 * 32 * 17 * 64 + 2 * 8 * 64 * 64 + 2 * 4 * 2 * 4 * 64; // 139264
    prep_weights<<<(prep_threads + 255) / 256, 256, 0, stream>>>(U, V, C, gateW, ws);
    dcn_main<<<kB / MTILE, 256, 0, stream>>>(x, bias, ws, out);
}